// Round 2
// baseline (2669.138 us; speedup 1.0000x reference)
//
#include <hip/hip_runtime.h>
#include <hip/hip_bf16.h>

#define DD 32
#define CC 128
#define N1 1024   // 2*H
#define ROWS 16
#define NBLK 128
#define THREADS 512

typedef float f32x4 __attribute__((ext_vector_type(4)));
typedef __bf16 bf16x8 __attribute__((ext_vector_type(8)));
typedef unsigned short u16x4 __attribute__((ext_vector_type(4)));

// workspace: per-wave-contiguous weight stream (1 KB frags), then w1c frags
// waves 0..3: 144 frags (8 L1 + 128 L2 + 8 L3); waves 4..7: 136 frags
#define STREAM_OFF 0
#define W1C_OFF (1120*1024)   // 1,146,880 B stream + 256 KB w1c = 1,409,024 B total

static __device__ __forceinline__ unsigned short f2bfu(float f) {
    __hip_bfloat16 h = __float2bfloat16(f);
    unsigned short u; __builtin_memcpy(&u, &h, 2); return u;
}
static __device__ __forceinline__ float bfu2f(unsigned short u) {
    unsigned int x = ((unsigned int)u) << 16;
    float f; __builtin_memcpy(&f, &x, 4); return f;
}

// fragment-linear LDS index (ushorts) for element block (row, k0=nt*16+rb4):
// byte(row,k) = (k>>5)*1024 + (((k>>3)&3)*16 + row)*16 + (k&7)*2
static __device__ __forceinline__ int hw_idx(int nt, int lane) {
    int row = lane & 15, wq = lane >> 4;
    return ((nt >> 1) << 9) + ((((nt << 1) + (wq >> 1)) & 3) * 16 + row) * 8 + (wq & 1) * 4;
}

// old-style pack (used for w1c): frag = nt*KT + kt; lane holds W[kt*32+(l>>4)*8+j][nt*16+(l&15)]
__global__ void pack_kernel(const float* __restrict__ W, __bf16* __restrict__ dst,
                            int Kreal, int N, int KT) {
    int frag = blockIdx.x;
    int lane = threadIdx.x;
    int nt = frag / KT, kt = frag - nt * KT;
    int kbase = kt * 32 + (lane >> 4) * 8;
    int n = nt * 16 + (lane & 15);
    union { unsigned short b[8]; int4 v; } u;
#pragma unroll
    for (int j = 0; j < 8; j++) {
        int k = kbase + j;
        float v = (k < Kreal) ? W[(size_t)k * N + n] : 0.f;
        u.b[j] = f2bfu(v);
    }
    *reinterpret_cast<int4*>((unsigned short*)dst + (size_t)frag * 512 + lane * 8) = u.v;
}

// per-wave consumption-order stream pack
__global__ void pack_stream(const float* __restrict__ W1, const float* __restrict__ W2,
                            const float* __restrict__ W3, __bf16* __restrict__ dst) {
    int g = blockIdx.x;        // global frag id == dst frag index
    int lane = threadIdx.x;
    int wv, seq;
    if (g < 576) { wv = g / 144; seq = g % 144; }
    else { int h = g - 576; wv = 4 + h / 136; seq = h % 136; }
    const float* W; int Kreal, N, kt, nt;
    if (seq < 8) {             // L1: theta rows of W1
        W = W1; Kreal = 32; N = N1; kt = 0;
        nt = wv * 4 + (seq >> 1) + (seq & 1) * 32;
    } else if (seq < 136) {    // L2
        int s = seq - 8;
        W = W2; Kreal = 512; N = N1;
        kt = ((s >> 3) & 3) * 4 + ((s & 7) >> 1);
        nt = wv * 4 + (s >> 5) + (s & 1) * 32;
    } else {                   // L3 (only waves 0..3 have these)
        int kk = seq - 136;
        W = W3; Kreal = 512; N = DD;
        kt = (wv >> 1) * 8 + kk; nt = wv & 1;
    }
    int kbase = kt * 32 + (lane >> 4) * 8;
    int n = nt * 16 + (lane & 15);
    union { unsigned short b[8]; int4 v; } u;
#pragma unroll
    for (int j = 0; j < 8; j++) {
        int k = kbase + j;
        float v = (k < Kreal) ? W[(size_t)k * N + n] : 0.f;
        u.b[j] = f2bfu(v);
    }
    *reinterpret_cast<int4*>((unsigned short*)dst + (size_t)g * 512 + lane * 8) = u.v;
}

#define MFMA(a, b, c) __builtin_amdgcn_mfma_f32_16x16x32_bf16((a), (b), (c), 0, 0, 0)

__global__ __launch_bounds__(THREADS, 2)
void ccnf_main(const float* __restrict__ theta0,
               const float* __restrict__ ctx,
               const float* __restrict__ W1,
               const float* __restrict__ b1,
               const float* __restrict__ b2g,
               const float* __restrict__ b3g,
               const char* __restrict__ wsb,
               const int* __restrict__ nsteps_p,
               float* __restrict__ out)
{
    __shared__ unsigned short hbuf1[16 * 512];   // h1, fragment-linear, 16 KB
    __shared__ unsigned short hbuf2[16 * 512];   // h2, fragment-linear, 16 KB
    __shared__ unsigned short cxt1[64 * 64 * 4]; // ctx@W1c+b1, per-lane D-records, 32 KB
    __shared__ unsigned short x_lds[512];        // theta stage input, fragment-linear, 1 KB
    __shared__ unsigned short w1t_s[N1];
    __shared__ unsigned short b2_s[N1];
    __shared__ float b3_s[DD];
    __shared__ float kpart[1024];

    const int tid  = threadIdx.x;
    const int lane = tid & 63;
    const int wv   = tid >> 6;
    const int row0 = blockIdx.x * ROWS;
    const int row  = lane & 15;
    const int wq   = lane >> 4;
    const int rb4  = wq * 4;
    const int kgrp = wq * 8;

    const bf16x8* ws  = reinterpret_cast<const bf16x8*>(wsb + STREAM_OFF);
    const bf16x8* w1c = reinterpret_cast<const bf16x8*>(wsb + W1C_OFF);
    const int basew = (wv < 4) ? wv * 144 : (576 + (wv - 4) * 136);

    // ---- prologue: stage ctx (reusing hbuf1), small vectors, theta ----
    unsigned short* ctx_tmp = hbuf1;   // [16][136] bf16
    for (int e = tid; e < ROWS * CC; e += THREADS) {
        int r = e >> 7, c2 = e & 127;
        ctx_tmp[r * 136 + c2] = f2bfu(ctx[(size_t)(row0 + r) * CC + c2]);
    }
    for (int c2 = tid; c2 < N1; c2 += THREADS) {
        w1t_s[c2] = f2bfu(W1[32 * N1 + c2]);
        b2_s[c2]  = f2bfu(b2g[c2]);
    }
    if (tid < DD) b3_s[tid] = b3g[tid];
    float th_reg = theta0[(size_t)row0 * DD + tid];
    { int d = tid & 31, r = tid >> 5;
      x_lds[((d >> 3) * 16 + r) * 8 + (d & 7)] = f2bfu(th_reg); }
    const int nst = nsteps_p[0];
    const float dt = 1.0f / (float)nst;
    __syncthreads();

    // ---- cxt1 = ctx @ W1[33:161] + b1 (transposed D, per-lane records) ----
#pragma unroll
    for (int pi = 0; pi < 8; pi++) {
        int nt = wv * 8 + pi;
        f32x4 acc = {0.f, 0.f, 0.f, 0.f};
#pragma unroll
        for (int ktc = 0; ktc < 4; ktc++) {
            bf16x8 cf = *reinterpret_cast<const bf16x8*>(&ctx_tmp[row * 136 + ktc * 32 + kgrp]);
            acc = MFMA(w1c[(nt * 4 + ktc) * 64 + lane], cf, acc);
        }
        float4 bq = *reinterpret_cast<const float4*>(&b1[nt * 16 + rb4]);
        u16x4 o;
        o[0] = f2bfu(acc[0] + bq.x); o[1] = f2bfu(acc[1] + bq.y);
        o[2] = f2bfu(acc[2] + bq.z); o[3] = f2bfu(acc[3] + bq.w);
        *reinterpret_cast<u16x4*>(&cxt1[(nt * 64 + lane) * 4]) = o;
    }

    // ---- initial weight prefetch: L1 frags + L2 chunks 0,1 ----
    bf16x8 wl1[8], wbuf[2][8];
#pragma unroll
    for (int j = 0; j < 8; j++) wl1[j]     = ws[(basew + j) * 64 + lane];
#pragma unroll
    for (int j = 0; j < 8; j++) wbuf[0][j] = ws[(basew + 8 + j) * 64 + lane];
#pragma unroll
    for (int j = 0; j < 8; j++) wbuf[1][j] = ws[(basew + 16 + j) * 64 + lane];
    __syncthreads();

    // ---- persistent RK4 loop ----
    float acck = 0.f;
    for (int step = 0; step < nst; ++step) {
        float tb = (float)step * dt;
#pragma unroll
        for (int s = 0; s < 4; ++s) {
            float tt = tb + ((s == 0) ? 0.f : (s == 3) ? dt : 0.5f * dt);

            // ---- Layer 1 (K=32 theta part + cxt1 + t*w1t), GLU -> hbuf1 ----
            bf16x8 xf = *reinterpret_cast<const bf16x8*>(&x_lds[lane * 8]);
#pragma unroll
            for (int p = 0; p < 4; p++) {
                int a_nt = wv * 4 + p, b_nt = a_nt + 32;
                f32x4 z = {0.f, 0.f, 0.f, 0.f};
                f32x4 zA = MFMA(wl1[2 * p],     xf, z);
                f32x4 zB = MFMA(wl1[2 * p + 1], xf, z);
                u16x4 cA = *reinterpret_cast<const u16x4*>(&cxt1[(a_nt * 64 + lane) * 4]);
                u16x4 cB = *reinterpret_cast<const u16x4*>(&cxt1[(b_nt * 64 + lane) * 4]);
                u16x4 tA = *reinterpret_cast<const u16x4*>(&w1t_s[a_nt * 16 + rb4]);
                u16x4 tB = *reinterpret_cast<const u16x4*>(&w1t_s[b_nt * 16 + rb4]);
                u16x4 o;
#pragma unroll
                for (int i = 0; i < 4; i++) {
                    float va = zA[i] + bfu2f(cA[i]) + tt * bfu2f(tA[i]);
                    float vb = zB[i] + bfu2f(cB[i]) + tt * bfu2f(tB[i]);
                    o[i] = f2bfu(va * (1.f / (1.f + __expf(-vb))));
                }
                *reinterpret_cast<u16x4*>(&hbuf1[hw_idx(a_nt, lane)]) = o;
            }
            __syncthreads();   // h1 ready

            // ---- Layer 2: pipelined weight stream, GLU -> hbuf2 ----
            f32x4 aA, aB;
#pragma unroll
            for (int c = 0; c < 16; c++) {
                if ((c & 3) == 0) { f32x4 z = {0.f,0.f,0.f,0.f}; aA = z; aB = z; }
#pragma unroll
                for (int t = 0; t < 4; t++) {
                    int kt = (c & 3) * 4 + t;
                    bf16x8 hf = *reinterpret_cast<const bf16x8*>(&hbuf1[kt * 512 + lane * 8]);
                    aA = MFMA(wbuf[c & 1][2 * t],     hf, aA);
                    aB = MFMA(wbuf[c & 1][2 * t + 1], hf, aB);
                }
                // refill this buffer: chunk c+2, or next-stage chunks 0/1 at the tail
                int nf = (c < 14) ? (c + 2) : (c - 14);
#pragma unroll
                for (int j = 0; j < 8; j++)
                    wbuf[c & 1][j] = ws[(basew + 8 + nf * 8 + j) * 64 + lane];
                if (c == 12 && wv < 4) {   // prefetch L3 frags into wl1 (freed after L1)
#pragma unroll
                    for (int j = 0; j < 8; j++) wl1[j] = ws[(basew + 136 + j) * 64 + lane];
                }
                if ((c & 3) == 3) {        // GLU epilogue for this p
                    int p = c >> 2;
                    int a_nt = wv * 4 + p, b_nt = a_nt + 32;
                    u16x4 bA = *reinterpret_cast<const u16x4*>(&b2_s[a_nt * 16 + rb4]);
                    u16x4 bB = *reinterpret_cast<const u16x4*>(&b2_s[b_nt * 16 + rb4]);
                    u16x4 o;
#pragma unroll
                    for (int i = 0; i < 4; i++) {
                        float va = aA[i] + bfu2f(bA[i]);
                        float vb = aB[i] + bfu2f(bB[i]);
                        o[i] = f2bfu(va * (1.f / (1.f + __expf(-vb))));
                    }
                    *reinterpret_cast<u16x4*>(&hbuf2[hw_idx(a_nt, lane)]) = o;
                }
            }
            __syncthreads();   // h2 ready

            // ---- Layer 3: k = h2 @ W3 + b3 (waves 0..3) ----
            if (wv < 4) {
                int nt3 = wv & 1, kh = wv >> 1;
                f32x4 acc = {0.f, 0.f, 0.f, 0.f};
#pragma unroll
                for (int kk = 0; kk < 8; kk++) {
                    int kt = kh * 8 + kk;
                    bf16x8 hf = *reinterpret_cast<const bf16x8*>(&hbuf2[kt * 512 + lane * 8]);
                    acc = MFMA(wl1[kk], hf, acc);
                }
                float4 kq;
                kq.x = acc[0] + ((kh == 0) ? b3_s[nt3 * 16 + rb4 + 0] : 0.f);
                kq.y = acc[1] + ((kh == 0) ? b3_s[nt3 * 16 + rb4 + 1] : 0.f);
                kq.z = acc[2] + ((kh == 0) ? b3_s[nt3 * 16 + rb4 + 2] : 0.f);
                kq.w = acc[3] + ((kh == 0) ? b3_s[nt3 * 16 + rb4 + 3] : 0.f);
                *reinterpret_cast<float4*>(&kpart[kh * 512 + row * 32 + nt3 * 16 + rb4]) = kq;
            }
            // refill wl1 with next-stage L1 frags (all waves; arrives across barriers)
#pragma unroll
            for (int j = 0; j < 8; j++) wl1[j] = ws[(basew + j) * 64 + lane];
            __syncthreads();   // kpart ready

            // ---- RK4 combine (thread owns element tid: row=tid>>5, d=tid&31) ----
            {
                float kv = kpart[tid] + kpart[512 + tid];
                float xe;
                if (s == 0)      { acck = kv;          xe = th_reg + 0.5f * dt * kv; }
                else if (s == 1) { acck += 2.f * kv;   xe = th_reg + 0.5f * dt * kv; }
                else if (s == 2) { acck += 2.f * kv;   xe = th_reg + dt * kv; }
                else             { th_reg += (dt / 6.f) * (acck + kv); xe = th_reg; }
                int d = tid & 31, r = tid >> 5;
                x_lds[((d >> 3) * 16 + r) * 8 + (d & 7)] = f2bfu(xe);
            }
            __syncthreads();   // x ready; buffers free for next stage
        }
    }
    out[(size_t)row0 * DD + tid] = th_reg;
}

extern "C" void kernel_launch(void* const* d_in, const int* in_sizes, int n_in,
                              void* d_out, int out_size, void* d_ws, size_t ws_size,
                              hipStream_t stream) {
    const float* theta0 = (const float*)d_in[0];
    const float* ctx    = (const float*)d_in[1];
    const float* W1     = (const float*)d_in[2];
    const float* b1     = (const float*)d_in[3];
    const float* W2     = (const float*)d_in[4];
    const float* b2     = (const float*)d_in[5];
    const float* W3     = (const float*)d_in[6];
    const float* b3     = (const float*)d_in[7];
    const int*   nst    = (const int*)d_in[8];
    float* out = (float*)d_out;
    char*  ws  = (char*)d_ws;

    __bf16* wstream = (__bf16*)(ws + STREAM_OFF);
    __bf16* w1cp    = (__bf16*)(ws + W1C_OFF);

    pack_stream<<<1120, 64, 0, stream>>>(W1, W2, W3, wstream);
    pack_kernel<<<256,  64, 0, stream>>>(W1 + 33 * N1, w1cp, CC, N1, 4);

    ccnf_main<<<NBLK, THREADS, 0, stream>>>(theta0, ctx, W1, b1, b2, b3,
                                            (const char*)ws, nst, out);
}

// Round 4
// 2489.537 us; speedup vs baseline: 1.0721x; 1.0721x over previous
//
#include <hip/hip_runtime.h>
#include <hip/hip_bf16.h>

#define DD 32
#define CC 128
#define N1 1024   // 2*H
#define ROWS 16
#define NBLK 128
#define THREADS 512

#define FRAGS_PER_WAVE 140   // 8 L1 + 128 L2 + 4 L3
#define RING 14              // ring slots (1 KB frags); divides 140; B+D-1 = 11 < 14

typedef float f32x4 __attribute__((ext_vector_type(4)));
typedef __bf16 bf16x8 __attribute__((ext_vector_type(8)));
typedef unsigned short u16x4 __attribute__((ext_vector_type(4)));

// workspace: per-wave consumption-order stream (8 waves x 140 frags x 1 KB), then w1c frags
#define STREAM_OFF 0
#define W1C_OFF (1120*1024)   // + 256 KB w1c -> 1,409,024 B total

static __device__ __forceinline__ unsigned short f2bfu(float f) {
    __hip_bfloat16 h = __float2bfloat16(f);
    unsigned short u; __builtin_memcpy(&u, &h, 2); return u;
}
static __device__ __forceinline__ float bfu2f(unsigned short u) {
    unsigned int x = ((unsigned int)u) << 16;
    float f; __builtin_memcpy(&f, &x, 4); return f;
}

// fragment-linear LDS index (ushorts) for GLU output write (verified round 2)
static __device__ __forceinline__ int hw_idx(int nt, int lane) {
    int row = lane & 15, wq = lane >> 4;
    return ((nt >> 1) << 9) + ((((nt << 1) + (wq >> 1)) & 3) * 16 + row) * 8 + (wq & 1) * 4;
}

// old-style pack (used for w1c): frag = nt*4 + kt
__global__ void pack_kernel(const float* __restrict__ W, __bf16* __restrict__ dst,
                            int Kreal, int N, int KT) {
    int frag = blockIdx.x;
    int lane = threadIdx.x;
    int nt = frag / KT, kt = frag - nt * KT;
    int kbase = kt * 32 + (lane >> 4) * 8;
    int n = nt * 16 + (lane & 15);
    union { unsigned short b[8]; int4 v; } u;
#pragma unroll
    for (int j = 0; j < 8; j++) {
        int k = kbase + j;
        float v = (k < Kreal) ? W[(size_t)k * N + n] : 0.f;
        u.b[j] = f2bfu(v);
    }
    *reinterpret_cast<int4*>((unsigned short*)dst + (size_t)frag * 512 + lane * 8) = u.v;
}

// per-wave consumption-order stream pack: wave wv owns frags [wv*140, wv*140+140)
__global__ void pack_stream(const float* __restrict__ W1, const float* __restrict__ W2,
                            const float* __restrict__ W3, __bf16* __restrict__ dst) {
    int g = blockIdx.x;        // 0..1119
    int lane = threadIdx.x;
    int wv = g / FRAGS_PER_WAVE, seq = g % FRAGS_PER_WAVE;
    const float* W; int Kreal, N, kt, nt;
    if (seq < 8) {             // L1: theta rows of W1 (K=32)
        int p = seq >> 1, ab = seq & 1;
        W = W1; Kreal = 32; N = N1; kt = 0;
        nt = wv * 4 + p + 32 * ab;
    } else if (seq < 136) {    // L2: kt-major, (p,ab)-minor
        int s = seq - 8;
        int ktt = s >> 3, j = s & 7, p = j >> 1, ab = j & 1;
        W = W2; Kreal = 512; N = N1;
        kt = ktt; nt = wv * 4 + p + 32 * ab;
    } else {                   // L3: wave -> (nt3 = wv&1, kq = wv>>1), kt = kq*4 + q
        int q = seq - 136;
        W = W3; Kreal = 512; N = DD;
        kt = (wv >> 1) * 4 + q; nt = wv & 1;
    }
    int kbase = kt * 32 + (lane >> 4) * 8;
    int n = nt * 16 + (lane & 15);
    union { unsigned short b[8]; int4 v; } u;
#pragma unroll
    for (int j = 0; j < 8; j++) {
        int k = kbase + j;
        float v = (k < Kreal) ? W[(size_t)k * N + n] : 0.f;
        u.b[j] = f2bfu(v);
    }
    *reinterpret_cast<int4*>((unsigned short*)dst + (size_t)g * 512 + lane * 8) = u.v;
}

#define MFMA(a, b, c) __builtin_amdgcn_mfma_f32_16x16x32_bf16((a), (b), (c), 0, 0, 0)

// async DMA stage of frag f into the wave's ring slot (f % 140) % 14
#define STAGE(fexpr) do {                                                          \
    const int _f = (fexpr);                                                        \
    const int _fw = (_f >= FRAGS_PER_WAVE) ? (_f - FRAGS_PER_WAVE) : _f;           \
    __builtin_amdgcn_global_load_lds(                                              \
        (const __attribute__((address_space(1))) void*)(stream_lane + (size_t)_fw * 1024), \
        (__attribute__((address_space(3))) void*)(ring_w + (_fw % RING) * 512),    \
        16, 0, 0);                                                                 \
} while (0)

// fence so STAGE groups can't hoist above earlier ds_reads of the slots they overwrite
#define SBAR() __builtin_amdgcn_sched_barrier(0)

// wait until all but the 8 newest DMAs are complete; fence the scheduler
#define WAITV() do {                                   \
    asm volatile("s_waitcnt vmcnt(8)" ::: "memory");   \
    __builtin_amdgcn_sched_barrier(0);                 \
} while (0)

// block barrier WITHOUT vmcnt drain (ring DMAs are wave-private; cross-wave data is DS)
#define BARRIER() asm volatile("s_waitcnt lgkmcnt(0)\n\ts_barrier" ::: "memory")

__global__ __launch_bounds__(THREADS, 2)
void ccnf_main(const float* __restrict__ theta0,
               const float* __restrict__ ctx,
               const float* __restrict__ W1,
               const float* __restrict__ b1,
               const float* __restrict__ b2g,
               const float* __restrict__ b3g,
               const char* __restrict__ wsb,
               const int* __restrict__ nsteps_p,
               float* __restrict__ out)
{
    // LDS: ring 112 KB + hbuf1 16 KB + hbuf2 16 KB + x 1 KB + kpart 8 KB = 153 KB
    __shared__ unsigned short ring[8 * RING * 512];
    __shared__ unsigned short hbuf1[16 * 512];
    __shared__ unsigned short hbuf2[16 * 512];
    __shared__ unsigned short x_lds[512];
    __shared__ float kpart[4 * 512];

    const int tid  = threadIdx.x;
    const int lane = tid & 63;
    const int wv   = tid >> 6;
    const int row0 = blockIdx.x * ROWS;
    const int row  = lane & 15;
    const int rb4  = (lane >> 4) * 4;
    const int kgrp = (lane >> 4) * 8;

    const char* stream_lane = wsb + STREAM_OFF + ((size_t)wv * FRAGS_PER_WAVE) * 1024 + lane * 16;
    unsigned short* ring_w = ring + wv * (RING * 512);
    const bf16x8* w1c = reinterpret_cast<const bf16x8*>(wsb + W1C_OFF);

    // ---- prologue: stage ctx into hbuf1 head ([16][136] bf16) ----
    unsigned short* ctx_tmp = hbuf1;
    {
        int idx = tid * 4;                    // 2048 floats / 512 threads
        int r = idx >> 7, c = idx & 127;
        float4 cv = *reinterpret_cast<const float4*>(&ctx[(size_t)(row0 + r) * CC + c]);
        ctx_tmp[r * 136 + c + 0] = f2bfu(cv.x);
        ctx_tmp[r * 136 + c + 1] = f2bfu(cv.y);
        ctx_tmp[r * 136 + c + 2] = f2bfu(cv.z);
        ctx_tmp[r * 136 + c + 3] = f2bfu(cv.w);
    }
    float th_reg = theta0[(size_t)row0 * DD + tid];
    { int d = tid & 31, r = tid >> 5;
      x_lds[((d >> 3) * 16 + r) * 8 + (d & 7)] = f2bfu(th_reg); }
    const int nst = nsteps_p[0];
    const float dt = 1.0f / (float)nst;
    __syncthreads();

    // ---- per-wave register constants: cxt1, w1t, b2 (this wave's 8 ntiles), b3 ----
    u16x4 c1r[4][2], w1tr[4][2], b2r[4][2];
#pragma unroll
    for (int p = 0; p < 4; p++) {
#pragma unroll
        for (int ab = 0; ab < 2; ab++) {
            int nt = wv * 4 + p + 32 * ab;
            f32x4 a = {0.f, 0.f, 0.f, 0.f};
#pragma unroll
            for (int ktc = 0; ktc < 4; ktc++) {
                bf16x8 cf = *reinterpret_cast<const bf16x8*>(&ctx_tmp[row * 136 + ktc * 32 + kgrp]);
                a = MFMA(w1c[(nt * 4 + ktc) * 64 + lane], cf, a);
            }
            float4 b1q = *reinterpret_cast<const float4*>(&b1[nt * 16 + rb4]);
            float4 wtq = *reinterpret_cast<const float4*>(&W1[32 * N1 + nt * 16 + rb4]);
            float4 b2q = *reinterpret_cast<const float4*>(&b2g[nt * 16 + rb4]);
            c1r[p][ab][0] = f2bfu(a[0] + b1q.x); c1r[p][ab][1] = f2bfu(a[1] + b1q.y);
            c1r[p][ab][2] = f2bfu(a[2] + b1q.z); c1r[p][ab][3] = f2bfu(a[3] + b1q.w);
            w1tr[p][ab][0] = f2bfu(wtq.x); w1tr[p][ab][1] = f2bfu(wtq.y);
            w1tr[p][ab][2] = f2bfu(wtq.z); w1tr[p][ab][3] = f2bfu(wtq.w);
            b2r[p][ab][0] = f2bfu(b2q.x); b2r[p][ab][1] = f2bfu(b2q.y);
            b2r[p][ab][2] = f2bfu(b2q.z); b2r[p][ab][3] = f2bfu(b2q.w);
        }
    }
    const int nt3 = wv & 1, kq = wv >> 1;
    float4 b3r = *reinterpret_cast<const float4*>(&b3g[nt3 * 16 + rb4]);

    __syncthreads();   // ctx_tmp fully consumed; hbuf1 free for h1

    // ---- warm the ring: frags 0..7 (8 outstanding = pipeline depth) ----
#pragma unroll
    for (int f = 0; f < 8; f++) STAGE(f);

    // ---- persistent RK4 loop ----
    float acck = 0.f;
    for (int step = 0; step < nst; ++step) {
        float tb = (float)step * dt;
#pragma unroll 1
        for (int s = 0; s < 4; ++s) {
            float tt = tb + ((s == 0) ? 0.f : (s == 3) ? dt : 0.5f * dt);

            // ---- L1: frags 0..7 (B=2/iter), GLU -> hbuf1 ----
            bf16x8 xf = *reinterpret_cast<const bf16x8*>(&x_lds[lane * 8]);
#pragma unroll
            for (int p = 0; p < 4; p++) {
                SBAR();
                STAGE(2 * p + 8); STAGE(2 * p + 9);
                WAITV();
                bf16x8 wfA = *reinterpret_cast<const bf16x8*>(ring_w + ((2 * p) % RING) * 512 + lane * 8);
                bf16x8 wfB = *reinterpret_cast<const bf16x8*>(ring_w + ((2 * p + 1) % RING) * 512 + lane * 8);
                f32x4 z = {0.f, 0.f, 0.f, 0.f};
                f32x4 zA = MFMA(wfA, xf, z);
                f32x4 zB = MFMA(wfB, xf, z);
                u16x4 o;
#pragma unroll
                for (int i = 0; i < 4; i++) {
                    float va = zA[i] + bfu2f(c1r[p][0][i]) + tt * bfu2f(w1tr[p][0][i]);
                    float vb = zB[i] + bfu2f(c1r[p][1][i]) + tt * bfu2f(w1tr[p][1][i]);
                    o[i] = f2bfu(va * (1.f / (1.f + __expf(-vb))));
                }
                *reinterpret_cast<u16x4*>(&hbuf1[hw_idx(wv * 4 + p, lane)]) = o;
            }
            BARRIER();   // h1 ready

            // ---- L2: frags 8..135 in 32 half-batches of 4 (B=4, D=8) ----
            f32x4 acc[4][2];
#pragma unroll
            for (int p = 0; p < 4; p++) {
                f32x4 z = {0.f, 0.f, 0.f, 0.f};
                acc[p][0] = z; acc[p][1] = z;
            }
#pragma unroll
            for (int m = 0; m < 32; ++m) {
                const int kt = m >> 1, h = m & 1;
                SBAR();
                STAGE(16 + 4 * m + 0); STAGE(16 + 4 * m + 1);
                STAGE(16 + 4 * m + 2); STAGE(16 + 4 * m + 3);
                WAITV();
                bf16x8 hf = *reinterpret_cast<const bf16x8*>(&hbuf1[kt * 512 + lane * 8]);
#pragma unroll
                for (int jj = 0; jj < 4; ++jj) {
                    const int fr = 8 + 4 * m + jj;      // frag being consumed
                    const int j  = h * 4 + jj;          // (p,ab) index within kt
                    bf16x8 wf = *reinterpret_cast<const bf16x8*>(ring_w + (fr % RING) * 512 + lane * 8);
                    acc[j >> 1][j & 1] = MFMA(wf, hf, acc[j >> 1][j & 1]);
                }
            }
            // GLU epilogue -> hbuf2
#pragma unroll
            for (int p = 0; p < 4; p++) {
                u16x4 o;
#pragma unroll
                for (int i = 0; i < 4; i++) {
                    float va = acc[p][0][i] + bfu2f(b2r[p][0][i]);
                    float vb = acc[p][1][i] + bfu2f(b2r[p][1][i]);
                    o[i] = f2bfu(va * (1.f / (1.f + __expf(-vb))));
                }
                *reinterpret_cast<u16x4*>(&hbuf2[hw_idx(wv * 4 + p, lane)]) = o;
            }
            BARRIER();   // h2 ready

            // ---- L3: frags 136..139 (all 8 waves: nt3 = wv&1, kq = wv>>1) ----
            SBAR();
#pragma unroll
            for (int q = 0; q < 4; ++q) STAGE(4 + q);   // next-eval frags 4..7
            WAITV();
            {
                f32x4 a3 = {0.f, 0.f, 0.f, 0.f};
#pragma unroll
                for (int q = 0; q < 4; ++q) {
                    int kt3 = kq * 4 + q;
                    bf16x8 h2f = *reinterpret_cast<const bf16x8*>(&hbuf2[kt3 * 512 + lane * 8]);
                    bf16x8 wf = *reinterpret_cast<const bf16x8*>(ring_w + ((136 + q) % RING) * 512 + lane * 8);
                    a3 = MFMA(wf, h2f, a3);
                }
                float4 kv4;
                kv4.x = a3[0] + ((kq == 0) ? b3r.x : 0.f);
                kv4.y = a3[1] + ((kq == 0) ? b3r.y : 0.f);
                kv4.z = a3[2] + ((kq == 0) ? b3r.z : 0.f);
                kv4.w = a3[3] + ((kq == 0) ? b3r.w : 0.f);
                *reinterpret_cast<float4*>(&kpart[kq * 512 + row * 32 + nt3 * 16 + rb4]) = kv4;
            }
            BARRIER();   // kpart ready

            // ---- RK4 combine (thread owns element tid: r = tid>>5, d = tid&31) ----
            {
                float kv = kpart[tid] + kpart[512 + tid] + kpart[1024 + tid] + kpart[1536 + tid];
                float xe;
                if (s == 0)      { acck = kv;          xe = th_reg + 0.5f * dt * kv; }
                else if (s == 1) { acck += 2.f * kv;   xe = th_reg + 0.5f * dt * kv; }
                else if (s == 2) { acck += 2.f * kv;   xe = th_reg + dt * kv; }
                else             { th_reg += (dt / 6.f) * (acck + kv); xe = th_reg; }
                int d = tid & 31, r = tid >> 5;
                x_lds[((d >> 3) * 16 + r) * 8 + (d & 7)] = f2bfu(xe);
            }
            BARRIER();   // x ready; hbuf1/hbuf2/kpart free
        }
    }
    out[(size_t)row0 * DD + tid] = th_reg;
}

extern "C" void kernel_launch(void* const* d_in, const int* in_sizes, int n_in,
                              void* d_out, int out_size, void* d_ws, size_t ws_size,
                              hipStream_t stream) {
    const float* theta0 = (const float*)d_in[0];
    const float* ctx    = (const float*)d_in[1];
    const float* W1     = (const float*)d_in[2];
    const float* b1     = (const float*)d_in[3];
    const float* W2     = (const float*)d_in[4];
    const float* b2     = (const float*)d_in[5];
    const float* W3     = (const float*)d_in[6];
    const float* b3     = (const float*)d_in[7];
    const int*   nst    = (const int*)d_in[8];
    float* out = (float*)d_out;
    char*  ws  = (char*)d_ws;

    __bf16* wstream = (__bf16*)(ws + STREAM_OFF);
    __bf16* w1cp    = (__bf16*)(ws + W1C_OFF);

    pack_stream<<<1120, 64, 0, stream>>>(W1, W2, W3, wstream);
    pack_kernel<<<256,  64, 0, stream>>>(W1 + 33 * N1, w1cp, CC, N1, 4);

    ccnf_main<<<NBLK, THREADS, 0, stream>>>(theta0, ctx, W1, b1, b2, b3,
                                            (const char*)ws, nst, out);
}